// Round 9
// baseline (75.156 us; speedup 1.0000x reference)
//
#include <hip/hip_runtime.h>
#include <hip/hip_bf16.h>
#include <stdint.h>

// MQA attention, bf16 MFMA pipeline.
// B=2, S=2048, D_MODEL=1024, H=16, DK=64. Causal mask applied analytically.
//
// R22: attn occupancy/uniformity redesign. Diagnosis across R18/R20/R21:
// nothing saturated; the (g+1,16-g) block pairing leaves each CU running a
// lone 8-wave block most of the time (2 waves/SIMD, latency-exposed).
// New k_attn: 1024 blocks x 4 waves (256 thr), 32KB LDS -> 4 blocks/CU,
// 16 waves/CU CONSTANT, per-CU quad {g,15-g,16+g,31-g} (64-q chunks) = 66
// phases uniform. Same R13 fragment algebra with kv-tiles 32 (K 4KB tiles;
// V staged as 64-kv granules, g2 picks the chunk half). One P-frag per
// q-group -> vt permutation changes to pi32 (bit perm [c5 c2 c4 c3 c1 c0]),
// k_vt updated to match. 8 ds_reads + 18 MFMA per wave-phase. gemm/prep
// unchanged (R15-proven).

typedef __attribute__((ext_vector_type(8))) short short8;
typedef __attribute__((ext_vector_type(4))) short short4_t;
typedef __attribute__((ext_vector_type(4))) float f32x4;

#define MFMA16(a, b, c) __builtin_amdgcn_mfma_f32_16x16x32_bf16((a), (b), (c), 0, 0, 0)

// scale (1/sqrt(dk)) * log2(e), folded into wq/bq at prep time
#define SCALE_Q 0.1803368801111244f

__device__ inline void gload_lds16(const void* g, void* l) {
  __builtin_amdgcn_global_load_lds(
      (const __attribute__((address_space(1))) void*)g,
      (__attribute__((address_space(3))) void*)l, 16, 0, 0);
}

__device__ inline float fast_exp2(float x) {
  float r;
  asm("v_exp_f32 %0, %1" : "=v"(r) : "v"(x));
  return r;
}

// float -> bf16 bits, round-to-nearest-even (inputs are finite)
__device__ inline short f2bf(float f) {
  union { float f; uint32_t u; } v;
  v.f = f;
  uint32_t u = v.u;
  return (short)((u + 0x7fffu + ((u >> 16) & 1u)) >> 16);
}

// pack two f32 -> 2 bf16 (RNE), one instruction
__device__ inline uint32_t pk_bf16(float lo, float hi) {
  uint32_t r;
  asm("v_cvt_pk_bf16_f32 %0, %1, %2" : "=v"(r) : "v"(lo), "v"(hi));
  return r;
}

__device__ inline int imin(int a, int b) { return a < b ? a : b; }

// ---------------- fused prep kernel ----------------
// blocks [0,544): weight transpose 64x64 tiles via LDS (heavy -> dispatched
// first so they overlap the casts instead of trailing them); block 544:
// fused bias; [545,1057): x cast, 4 x 2048-elem chunks per block (MLP).
__global__ __launch_bounds__(256) void k_prep(
    const float* __restrict__ x, const float* __restrict__ wq,
    const float* __restrict__ wk, const float* __restrict__ wv,
    const float* __restrict__ bq, const float* __restrict__ bk,
    const float* __restrict__ bv, const float* __restrict__ wo,
    short* __restrict__ xb, short* __restrict__ wqkvt,
    float* __restrict__ biasq, short* __restrict__ wot) {
  const int blk = blockIdx.x;
  const int t = threadIdx.x;
  if (blk >= 545) {
    const int base = (blk - 545) * 8192;
#pragma unroll
    for (int it = 0; it < 4; ++it) {
      const int i = base + it * 2048 + t * 8;
      const float* xp = x + i;
      short8 o;
#pragma unroll
      for (int j = 0; j < 8; ++j) o[j] = f2bf(xp[j]);
      *(short8*)(xb + i) = o;
    }
    return;
  }
  if (blk == 544) {
    for (int idx = t; idx < 1152; idx += 256)
      biasq[idx] = idx < 1024 ? bq[idx] * SCALE_Q
                              : (idx < 1088 ? bk[idx - 1024] : bv[idx - 1088]);
    return;
  }
  __shared__ float lds[64][65];
  const int j = blk;
  const float* src;
  short* dst;
  int ncol, k0, n0, row0;
  float sc = 1.f;
  if (j < 256)      { src = wq; dst = wqkvt; ncol = 1024; k0 = (j >> 4) * 64;
                      n0 = (j & 15) * 64; row0 = n0; sc = SCALE_Q; }
  else if (j < 272) { src = wk; dst = wqkvt; ncol = 64; k0 = (j - 256) * 64;
                      n0 = 0; row0 = 1024; }
  else if (j < 288) { src = wv; dst = wqkvt; ncol = 64; k0 = (j - 272) * 64;
                      n0 = 0; row0 = 1088; }
  else              { int jj = j - 288; src = wo; dst = wot; ncol = 1024;
                      k0 = (jj >> 4) * 64; n0 = (jj & 15) * 64; row0 = n0; }
#pragma unroll
  for (int i = 0; i < 4; ++i) {
    int f = i * 256 + t;
    int k = f >> 4, c = f & 15;
    const float* sp = src + (size_t)(k0 + k) * ncol + n0 + c * 4;
#pragma unroll
    for (int q = 0; q < 4; ++q) lds[k][c * 4 + q] = sp[q];
  }
  __syncthreads();
#pragma unroll
  for (int i = 0; i < 2; ++i) {
    int f = i * 256 + t;
    int n = f >> 3, kc = f & 7;
    short8 o;
#pragma unroll
    for (int q = 0; q < 8; ++q) o[q] = f2bf(lds[kc * 8 + q][n] * sc);
    *(short8*)(dst + (size_t)(row0 + n) * 1024 + k0 + kc * 8) = o;
  }
}

// ---------------- V transpose via LDS (coalesced both sides) ----------------
// vt[d][32T + c] = V[32T + pi32(c)][d],
// pi32: bit permutation [c4 c1 c3 c2 c0] within 32-kv tiles (bijective);
// expressed on 64-col blocks: pi(c) = 32*(c>>5) + 16*((c>>2)&1)
//                                   + 4*((c>>3)&3) + (c&3)
__global__ __launch_bounds__(256) void k_vt(const short* __restrict__ qkv,
                                            short* __restrict__ vt) {
  __shared__ short lds[64][72];
  const int blk = blockIdx.x;
  const int b = blk >> 5, T = blk & 31;
  const int t = threadIdx.x;
#pragma unroll
  for (int i = 0; i < 2; ++i) {
    int f = i * 256 + t;
    int row = f >> 3, c = f & 7;
    short8 v = *(const short8*)(qkv +
        (size_t)(b * 2048 + T * 64 + row) * 1152 + 1088 + c * 8);
    *(short8*)(&lds[row][c * 8]) = v;
  }
  __syncthreads();
#pragma unroll
  for (int i = 0; i < 2; ++i) {
    int f = i * 256 + t;
    int d = f & 63, g = f >> 6;
    short8 o;
#pragma unroll
    for (int j = 0; j < 8; ++j) {
      int c = g * 8 + j;
      int pi = 32 * (c >> 5) + 16 * ((c >> 2) & 1) + 4 * ((c >> 3) & 3) + (c & 3);
      o[j] = lds[pi][d];
    }
    *(short8*)(vt + (size_t)(b * 64 + d) * 2048 + T * 64 + g * 8) = o;
  }
}

// ---------------- GEMM: tile 64x128 (MxN), BK=64, double-buffered ----------
// C[M][ldc] = A[M][1024] @ Bt[N][1024]^T + bias. 4 waves; wave w covers all 64
// rows x 32 cols. Counted vmcnt(6), one raw barrier per K-step, XOR-swizzled
// LDS (slot (row,c) holds global chunk c^(row&7)) for conflict-free b128 reads.
__global__ __launch_bounds__(256, 3) void k_gemm(const short* __restrict__ A,
                                                 const short* __restrict__ Bt,
                                                 const float* __restrict__ bias,
                                                 void* __restrict__ C, int ldc,
                                                 int out_bf16) {
  __shared__ short As[2][4096];  // [64 rows][64 k] 8KB each
  __shared__ short Bs[2][8192];  // [128 rows][64 k] 16KB each
  const int t = threadIdx.x;
  const int w = t >> 6, l = t & 63;
  const int l15 = l & 15, lhi = l >> 4;
  const int m0 = blockIdx.x * 64, n0 = blockIdx.y * 128;

  f32x4 acc[4][2];
#pragma unroll
  for (int i = 0; i < 4; ++i)
#pragma unroll
    for (int j = 0; j < 2; ++j)
#pragma unroll
      for (int r = 0; r < 4; ++r) acc[i][j][r] = 0.f;

  const int fA0 = w * 64 + l;
  const int rA0 = fA0 >> 3, gA0 = (fA0 & 7) ^ (rA0 & 7);
  const int fA1 = fA0 + 256;
  const int rA1 = fA1 >> 3, gA1 = (fA1 & 7) ^ (rA1 & 7);

  const int aoff = l15 * 128 + ((lhi ^ (l15 & 7)) << 4);
  const int coff = l15 * 128 + (((4 + lhi) ^ (l15 & 7)) << 4);

#define GEMM_STAGE(buf, k0)                                                    \
  {                                                                            \
    gload_lds16(A + (size_t)(m0 + rA0) * 1024 + (k0) + gA0 * 8,               \
                &As[buf][w * 512]);                                            \
    gload_lds16(A + (size_t)(m0 + rA1) * 1024 + (k0) + gA1 * 8,               \
                &As[buf][2048 + w * 512]);                                     \
    _Pragma("unroll")                                                          \
    for (int q = 0; q < 4; ++q) {                                              \
      int f = q * 256 + fA0;                                                   \
      int r = f >> 3, gc = (f & 7) ^ (r & 7);                                  \
      gload_lds16(Bt + (size_t)(n0 + r) * 1024 + (k0) + gc * 8,               \
                  &Bs[buf][q * 2048 + w * 512]);                               \
    }                                                                          \
  }

  GEMM_STAGE(0, 0);

  for (int ks = 0; ks < 16; ++ks) {
    const int nb = (ks + 1) & 1;
    GEMM_STAGE(nb, imin(ks + 1, 15) * 64);
    asm volatile("s_waitcnt vmcnt(6)" ::: "memory");

    const char* as = (const char*)&As[ks & 1][0];
    const char* bs = (const char*)&Bs[ks & 1][0];
    short8 afA[4], afB[4], bfA[2], bfB[2];
#pragma unroll
    for (int i = 0; i < 4; ++i) {
      afA[i] = *(const short8*)(as + i * 2048 + aoff);
      afB[i] = *(const short8*)(as + i * 2048 + coff);
    }
#pragma unroll
    for (int j = 0; j < 2; ++j) {
      bfA[j] = *(const short8*)(bs + (w * 32 + j * 16) * 128 + aoff);
      bfB[j] = *(const short8*)(bs + (w * 32 + j * 16) * 128 + coff);
    }
#pragma unroll
    for (int i = 0; i < 4; ++i)
#pragma unroll
      for (int j = 0; j < 2; ++j) {
        acc[i][j] = MFMA16(afA[i], bfA[j], acc[i][j]);
        acc[i][j] = MFMA16(afB[i], bfB[j], acc[i][j]);
      }
    __builtin_amdgcn_s_barrier();
  }
  asm volatile("s_waitcnt vmcnt(0)" ::: "memory");

#pragma unroll
  for (int j = 0; j < 2; ++j) {
    int col = n0 + w * 32 + j * 16 + l15;
    float bia = bias[col];
#pragma unroll
    for (int i = 0; i < 4; ++i) {
      int row0 = m0 + i * 16 + lhi * 4;
      if (out_bf16) {
#pragma unroll
        for (int r = 0; r < 4; ++r)
          ((short*)C)[(size_t)(row0 + r) * ldc + col] =
              (short)(pk_bf16(acc[i][j][r] + bia, 0.f) & 0xffff);
      } else {
#pragma unroll
        for (int r = 0; r < 4; ++r)
          ((float*)C)[(size_t)(row0 + r) * ldc + col] = acc[i][j][r] + bia;
      }
    }
  }
#undef GEMM_STAGE
}

// ---------------- flash attention v22 (uniform quads, 4 blocks/CU) ---------
// 1024 blocks x 4 waves (256 thr). Block handles one 64-q chunk cc; waves:
// qw=w&1 (32 q rows = two 16-row groups) x kv-group g2=w>>1 (even/odd 32-kv
// tiles). nph = cc+1 phases. Per-CU quad {g,15-g,16+g,31-g} -> 66 phases
// uniform; 4 blocks/CU (32KB LDS), 16 waves/CU constant. K LDS [g2][db]
// 4KB tiles; V [db] 8KB granules (g2 picks chunk half). Static-bias
// softmax -> kv-group merge is exact addition.
__global__ __launch_bounds__(256, 4) void k_attn(const short* __restrict__ qkv,
                                                 const short* __restrict__ vt,
                                                 short* __restrict__ attnb) {
  // LDS: K[g2][db] at g2*8192 + db*4096 (0..16K); V[db] at 16384 + db*8192.
  __shared__ char smem[32768];
  const int t = threadIdx.x;
  const int w = t >> 6, l = t & 63;
  const int l15 = l & 15, lhi = l >> 4;
  const int qw = w & 1, g2 = w >> 1;
  const int bx = blockIdx.x;
  const int o = bx >> 5, g = o & 7;
  // uniform quads: {g, 15-g, 16+g, 31-g} phases sum (g+1)+(16-g)+(17+g)+(32-g)=66
  const int cc = (o < 8) ? g : (o < 16) ? 15 - g : (o < 24) ? 16 + g : 31 - g;
  const int bh = bx & 31, b = bh >> 4, h = bh & 15;
  const int nph = cc + 1;
  const short* kb = qkv + (size_t)(b * 2048) * 1152 + 1024;
  const short* vb = vt + (size_t)b * 64 * 2048;

  // staging lane geometry; LDS slot (row, c) holds global chunk c ^ (row&7)
  const int gcol = (l & 7) ^ (l >> 3);
  const short* kS = kb + (size_t)(w * 8 + (l >> 3)) * 1152 + gcol * 8;   // 32 K rows
  const short* vS1 = vb + (size_t)(w * 16 + (l >> 3)) * 2048 + gcol * 8; // 64 d rows
  const short* vS2 = vS1 + (size_t)8 * 2048;

  // frag read byte offsets (row = f*16 + l15, row stride 128B)
  const int aoff = l15 * 128 + ((lhi ^ (l15 & 7)) << 4);
  const int coff = l15 * 128 + (((4 + lhi) ^ (l15 & 7)) << 4);

  short8 ones;
#pragma unroll
  for (int j = 0; j < 8; ++j) ones[j] = (short)0x3F80;  // bf16 1.0

  const int qbase = cc * 64 + qw * 32;   // wave's 32 q rows
  const int myq0 = qbase + l15;          // q-group A
  const int myq1 = qbase + 16 + l15;     // q-group B
  const int ttdiag = qbase >> 5;         // = 2cc + qw (32-kv tiles)

  const short* qp0 = qkv + (size_t)(b * 2048 + myq0) * 1152 + h * 64 + 8 * lhi;
  const short* qp1 = qkv + (size_t)(b * 2048 + myq1) * 1152 + h * 64 + 8 * lhi;
  short8 qa0 = *(const short8*)(qp0);
  short8 qc0 = *(const short8*)(qp0 + 32);
  short8 qa1 = *(const short8*)(qp1);
  short8 qc1 = *(const short8*)(qp1 + 32);

  f32x4 oo[2][4], o5a, o5b;
#pragma unroll
  for (int qg = 0; qg < 2; ++qg)
#pragma unroll
    for (int fd = 0; fd < 4; ++fd)
#pragma unroll
      for (int r = 0; r < 4; ++r) oo[qg][fd][r] = 0.f;
#pragma unroll
  for (int r = 0; r < 4; ++r) { o5a[r] = 0.f; o5b[r] = 0.f; }

  // stage K tiles (tl, tl+1) -> K[0][db], K[1][db]; V granule G -> V[db]
#define ASTAGE(db, tl, G)                                                      \
  {                                                                            \
    gload_lds16(kS + (size_t)(tl) * 36864, smem + (db) * 4096 + w * 1024);     \
    gload_lds16(kS + (size_t)((tl) + 1) * 36864,                               \
                smem + 8192 + (db) * 4096 + w * 1024);                         \
    gload_lds16(vS1 + (G) * 64, smem + 16384 + (db) * 8192 + w * 2048);        \
    gload_lds16(vS2 + (G) * 64, smem + 16384 + (db) * 8192 + w * 2048 + 1024); \
  }

  // prologue: tiles 0,1 + V granule 0 -> db 0
  ASTAGE(0, 0, 0);
  __syncthreads();

#pragma unroll 1
  for (int i = 0; i < nph; ++i) {
    // stage phase i+1 (K tiles 2i+2, 2i+3; V granule i+1)
    if (i + 1 < nph) {
      ASTAGE((i + 1) & 1, 2 * i + 2, i + 1);
      __builtin_amdgcn_sched_barrier(0);
    }

    const int tt = 2 * i + g2;
    const int cb = i & 1;

    // K frags (shared by both q-groups); S^T = K Q^T for both groups
    const char* kr = smem + g2 * 8192 + cb * 4096;
    f32x4 s0[2], s1[2];
    __builtin_amdgcn_s_setprio(1);
#pragma unroll
    for (int f = 0; f < 2; ++f) {
      short8 ka = *(const short8*)(kr + f * 2048 + aoff);
      short8 kc = *(const short8*)(kr + f * 2048 + coff);
      f32x4 z0 = {0.f, 0.f, 0.f, 0.f};
      z0 = MFMA16(ka, qa0, z0);
      z0 = MFMA16(kc, qc0, z0);
      s0[f] = z0;
      f32x4 z1 = {0.f, 0.f, 0.f, 0.f};
      z1 = MFMA16(ka, qa1, z1);
      z1 = MFMA16(kc, qc1, z1);
      s1[f] = z1;
    }
    __builtin_amdgcn_s_setprio(0);

    // causal mask (R13 semantics): elementwise whenever tile reaches the q
    // rows; fully-masked tile computed (exp -> 0 -> exact +0 contribution)
    if (tt >= ttdiag) {
      const int t0 = tt * 32;
#pragma unroll
      for (int f = 0; f < 2; ++f) {
        int kvb = t0 + f * 16 + lhi * 4;
#pragma unroll
        for (int r = 0; r < 4; ++r) {
          s0[f][r] = (kvb + r <= myq0) ? s0[f][r] : -1e30f;
          s1[f][r] = (kvb + r <= myq1) ? s1[f][r] : -1e30f;
        }
      }
    }

    // p = exp2(s), fixed zero bias (static-bias softmax)
#pragma unroll
    for (int f = 0; f < 2; ++f)
#pragma unroll
      for (int r = 0; r < 4; ++r) {
        s0[f][r] = fast_exp2(s0[f][r]);
        s1[f][r] = fast_exp2(s1[f][r]);
      }

    // one P b-frag per q-group: elems j -> (f=j>>2, r=j&3); vt's pi32
    // pre-permutation makes slot k hold V[pi32(k)] to match.
    union { short8 v; uint32_t d[4]; } pA0, pA1;
    pA0.d[0] = pk_bf16(s0[0][0], s0[0][1]);
    pA0.d[1] = pk_bf16(s0[0][2], s0[0][3]);
    pA0.d[2] = pk_bf16(s0[1][0], s0[1][1]);
    pA0.d[3] = pk_bf16(s0[1][2], s0[1][3]);
    pA1.d[0] = pk_bf16(s1[0][0], s1[0][1]);
    pA1.d[1] = pk_bf16(s1[0][2], s1[0][3]);
    pA1.d[2] = pk_bf16(s1[1][0], s1[1][1]);
    pA1.d[3] = pk_bf16(s1[1][2], s1[1][3]);

    // V frags: granule i, this wave's kv-half (g2) = chunk half of each row
    const char* vr = smem + 16384 + cb * 8192;
    const int voff = g2 ? coff : aoff;
    __builtin_amdgcn_s_setprio(1);
#pragma unroll
    for (int fd = 0; fd < 4; ++fd) {
      short8 va = *(const short8*)(vr + fd * 2048 + voff);
      oo[0][fd] = MFMA16(va, pA0.v, oo[0][fd]);
      oo[1][fd] = MFMA16(va, pA1.v, oo[1][fd]);
    }
    o5a = MFMA16(ones, pA0.v, o5a);
    o5b = MFMA16(ones, pA1.v, o5b);
    __builtin_amdgcn_s_setprio(0);

    __syncthreads();  // staged tiles landed; all reads of current bufs done
  }
#undef ASTAGE

  // merge kv-groups (exact addition thanks to fixed-bias softmax), write out.
  // scratch overlaps K/V bufs (safe: after final barrier, compute done).
  // 128 lanes x 34 floats = 17408B < 32KB.
  float* scr = (float*)smem;
  float* sp = scr + ((qw << 6) + l) * 34;
  if (g2 == 1) {
#pragma unroll
    for (int qg = 0; qg < 2; ++qg)
#pragma unroll
      for (int fd = 0; fd < 4; ++fd)
#pragma unroll
        for (int r = 0; r < 4; ++r) sp[qg * 16 + fd * 4 + r] = oo[qg][fd][r];
    sp[32] = o5a[0];
    sp[33] = o5b[0];
  }
  __syncthreads();
  if (g2 == 0) {
#pragma unroll
    for (int qg = 0; qg < 2; ++qg) {
      float lsum = (qg ? o5b[0] : o5a[0]) + sp[32 + qg];
      float inv = 1.f / lsum;
      int myq = qbase + qg * 16 + l15;
      short* op = attnb + (size_t)(b * 2048 + myq) * 1024 + h * 64;
#pragma unroll
      for (int fd = 0; fd < 4; ++fd) {
        union { short4_t s4; uint32_t d[2]; } ov;
        float v0 = (oo[qg][fd][0] + sp[qg * 16 + fd * 4 + 0]) * inv;
        float v1 = (oo[qg][fd][1] + sp[qg * 16 + fd * 4 + 1]) * inv;
        float v2 = (oo[qg][fd][2] + sp[qg * 16 + fd * 4 + 2]) * inv;
        float v3 = (oo[qg][fd][3] + sp[qg * 16 + fd * 4 + 3]) * inv;
        ov.d[0] = pk_bf16(v0, v1);
        ov.d[1] = pk_bf16(v2, v3);
        *(short4_t*)(op + fd * 16 + lhi * 4) = ov.s4;
      }
    }
  }
}

// ---------------- launch ----------------
extern "C" void kernel_launch(void* const* d_in, const int* in_sizes, int n_in,
                              void* d_out, int out_size, void* d_ws, size_t ws_size,
                              hipStream_t stream) {
  const float* x  = (const float*)d_in[0];
  // d_in[1] = mask (causal tril) -- applied analytically
  const float* wq = (const float*)d_in[2];
  const float* bq = (const float*)d_in[3];
  const float* wk = (const float*)d_in[4];
  const float* bk = (const float*)d_in[5];
  const float* wv = (const float*)d_in[6];
  const float* bv = (const float*)d_in[7];
  const float* wo = (const float*)d_in[8];
  const float* bo = (const float*)d_in[9];

  char* ws = (char*)d_ws;
  short* xb    = (short*)(ws + 0);          // [4096][1024] bf16   8 MB
  short* qkv   = (short*)(ws + 8388608);    // [4096][1152] bf16   9 MB
  short* wqkvt = (short*)(ws + 17825792);   // [1152][1024] bf16   2.25 MB
  short* wot   = (short*)(ws + 20185088);   // [1024][1024] bf16   2 MB
  short* vt    = (short*)(ws + 22282240);   // [2][64][2048] bf16  0.5 MB
  short* attnb = (short*)(ws + 22806528);   // [4096][1024] bf16   8 MB
  float* biasq = (float*)(ws + 31195136);   // [1152] f32

  k_prep<<<1057, 256, 0, stream>>>(x, wq, wk, wv, bq, bk, bv, wo,
                                   xb, wqkvt, biasq, wot);
  k_gemm<<<dim3(64, 9), 256, 0, stream>>>(xb, wqkvt, biasq, qkv, 1152, 1);
  k_vt<<<64, 256, 0, stream>>>(qkv, vt);
  k_attn<<<1024, 256, 0, stream>>>(qkv, vt, attnb);
  k_gemm<<<dim3(64, 8), 256, 0, stream>>>(attnb, wot, bo, d_out, 1024, 0);
}

// Round 10
// 69.661 us; speedup vs baseline: 1.0789x; 1.0789x over previous
//
#include <hip/hip_runtime.h>
#include <hip/hip_bf16.h>
#include <stdint.h>

// MQA attention, bf16 MFMA pipeline.
// B=2, S=2048, D_MODEL=1024, H=16, DK=64. Causal mask applied analytically.
//
// R23: R15-proven build + k_vt FUSED into gemm1's epilogue. gemm1 already
// holds every V element (cols 1088..1151, y=8 blocks) in registers; the
// separate transpose kernel re-read 1MB / re-wrote 0.5MB just to apply the
// pi permutation. Epilogue now writes vt directly: V row y lands at
// position pi^-1(y) = 32*y1+16*y3+8*y2+4*y5+2*y4+y0 (inverse of k_vt's
// pi, derived bit-by-bit); lane's 4-row group (y1y0=0) -> two aligned 4B
// packed stores at {pb, pb+1} and {pb+32, pb+33}. attn R13-exact; k_prep
// R15; k_gemm otherwise unchanged (vt_out=nullptr for gemm2).

typedef __attribute__((ext_vector_type(8))) short short8;
typedef __attribute__((ext_vector_type(4))) short short4_t;
typedef __attribute__((ext_vector_type(4))) float f32x4;

#define MFMA16(a, b, c) __builtin_amdgcn_mfma_f32_16x16x32_bf16((a), (b), (c), 0, 0, 0)

// scale (1/sqrt(dk)) * log2(e), folded into wq/bq at prep time
#define SCALE_Q 0.1803368801111244f

__device__ inline void gload_lds16(const void* g, void* l) {
  __builtin_amdgcn_global_load_lds(
      (const __attribute__((address_space(1))) void*)g,
      (__attribute__((address_space(3))) void*)l, 16, 0, 0);
}

__device__ inline float fast_exp2(float x) {
  float r;
  asm("v_exp_f32 %0, %1" : "=v"(r) : "v"(x));
  return r;
}

// float -> bf16 bits, round-to-nearest-even (inputs are finite)
__device__ inline short f2bf(float f) {
  union { float f; uint32_t u; } v;
  v.f = f;
  uint32_t u = v.u;
  return (short)((u + 0x7fffu + ((u >> 16) & 1u)) >> 16);
}

// pack two f32 -> 2 bf16 (RNE), one instruction
__device__ inline uint32_t pk_bf16(float lo, float hi) {
  uint32_t r;
  asm("v_cvt_pk_bf16_f32 %0, %1, %2" : "=v"(r) : "v"(lo), "v"(hi));
  return r;
}

__device__ inline int imin(int a, int b) { return a < b ? a : b; }

// ---------------- fused prep kernel ----------------
// blocks [0,544): weight transpose 64x64 tiles via LDS (heavy -> dispatched
// first so they overlap the casts instead of trailing them); block 544:
// fused bias; [545,1057): x cast, 4 x 2048-elem chunks per block (MLP).
__global__ __launch_bounds__(256) void k_prep(
    const float* __restrict__ x, const float* __restrict__ wq,
    const float* __restrict__ wk, const float* __restrict__ wv,
    const float* __restrict__ bq, const float* __restrict__ bk,
    const float* __restrict__ bv, const float* __restrict__ wo,
    short* __restrict__ xb, short* __restrict__ wqkvt,
    float* __restrict__ biasq, short* __restrict__ wot) {
  const int blk = blockIdx.x;
  const int t = threadIdx.x;
  if (blk >= 545) {
    const int base = (blk - 545) * 8192;
#pragma unroll
    for (int it = 0; it < 4; ++it) {
      const int i = base + it * 2048 + t * 8;
      const float* xp = x + i;
      short8 o;
#pragma unroll
      for (int j = 0; j < 8; ++j) o[j] = f2bf(xp[j]);
      *(short8*)(xb + i) = o;
    }
    return;
  }
  if (blk == 544) {
    for (int idx = t; idx < 1152; idx += 256)
      biasq[idx] = idx < 1024 ? bq[idx] * SCALE_Q
                              : (idx < 1088 ? bk[idx - 1024] : bv[idx - 1088]);
    return;
  }
  __shared__ float lds[64][65];
  const int j = blk;
  const float* src;
  short* dst;
  int ncol, k0, n0, row0;
  float sc = 1.f;
  if (j < 256)      { src = wq; dst = wqkvt; ncol = 1024; k0 = (j >> 4) * 64;
                      n0 = (j & 15) * 64; row0 = n0; sc = SCALE_Q; }
  else if (j < 272) { src = wk; dst = wqkvt; ncol = 64; k0 = (j - 256) * 64;
                      n0 = 0; row0 = 1024; }
  else if (j < 288) { src = wv; dst = wqkvt; ncol = 64; k0 = (j - 272) * 64;
                      n0 = 0; row0 = 1088; }
  else              { int jj = j - 288; src = wo; dst = wot; ncol = 1024;
                      k0 = (jj >> 4) * 64; n0 = (jj & 15) * 64; row0 = n0; }
#pragma unroll
  for (int i = 0; i < 4; ++i) {
    int f = i * 256 + t;
    int k = f >> 4, c = f & 15;
    const float* sp = src + (size_t)(k0 + k) * ncol + n0 + c * 4;
#pragma unroll
    for (int q = 0; q < 4; ++q) lds[k][c * 4 + q] = sp[q];
  }
  __syncthreads();
#pragma unroll
  for (int i = 0; i < 2; ++i) {
    int f = i * 256 + t;
    int n = f >> 3, kc = f & 7;
    short8 o;
#pragma unroll
    for (int q = 0; q < 8; ++q) o[q] = f2bf(lds[kc * 8 + q][n] * sc);
    *(short8*)(dst + (size_t)(row0 + n) * 1024 + k0 + kc * 8) = o;
  }
}

// ---------------- GEMM: tile 64x128 (MxN), BK=64, double-buffered ----------
// C[M][ldc] = A[M][1024] @ Bt[N][1024]^T + bias. 4 waves; wave w covers all 64
// rows x 32 cols. Counted vmcnt(6), one raw barrier per K-step, XOR-swizzled
// LDS (slot (row,c) holds global chunk c^(row&7)) for conflict-free b128 reads.
// vt_out != nullptr (gemm1): V columns (col >= 1088) are ALSO written
// transposed+permuted into vt: V row y -> position pi^-1(y),
// pi^-1(y) = 32*y1 + 16*y3 + 8*y2 + 4*y5 + 2*y4 + y0.
__global__ __launch_bounds__(256, 3) void k_gemm(const short* __restrict__ A,
                                                 const short* __restrict__ Bt,
                                                 const float* __restrict__ bias,
                                                 void* __restrict__ C, int ldc,
                                                 int out_bf16,
                                                 short* __restrict__ vt_out) {
  __shared__ short As[2][4096];  // [64 rows][64 k] 8KB each
  __shared__ short Bs[2][8192];  // [128 rows][64 k] 16KB each
  const int t = threadIdx.x;
  const int w = t >> 6, l = t & 63;
  const int l15 = l & 15, lhi = l >> 4;
  const int m0 = blockIdx.x * 64, n0 = blockIdx.y * 128;

  f32x4 acc[4][2];
#pragma unroll
  for (int i = 0; i < 4; ++i)
#pragma unroll
    for (int j = 0; j < 2; ++j)
#pragma unroll
      for (int r = 0; r < 4; ++r) acc[i][j][r] = 0.f;

  const int fA0 = w * 64 + l;
  const int rA0 = fA0 >> 3, gA0 = (fA0 & 7) ^ (rA0 & 7);
  const int fA1 = fA0 + 256;
  const int rA1 = fA1 >> 3, gA1 = (fA1 & 7) ^ (rA1 & 7);

  const int aoff = l15 * 128 + ((lhi ^ (l15 & 7)) << 4);
  const int coff = l15 * 128 + (((4 + lhi) ^ (l15 & 7)) << 4);

#define GEMM_STAGE(buf, k0)                                                    \
  {                                                                            \
    gload_lds16(A + (size_t)(m0 + rA0) * 1024 + (k0) + gA0 * 8,               \
                &As[buf][w * 512]);                                            \
    gload_lds16(A + (size_t)(m0 + rA1) * 1024 + (k0) + gA1 * 8,               \
                &As[buf][2048 + w * 512]);                                     \
    _Pragma("unroll")                                                          \
    for (int q = 0; q < 4; ++q) {                                              \
      int f = q * 256 + fA0;                                                   \
      int r = f >> 3, gc = (f & 7) ^ (r & 7);                                  \
      gload_lds16(Bt + (size_t)(n0 + r) * 1024 + (k0) + gc * 8,               \
                  &Bs[buf][q * 2048 + w * 512]);                               \
    }                                                                          \
  }

  GEMM_STAGE(0, 0);

  for (int ks = 0; ks < 16; ++ks) {
    const int nb = (ks + 1) & 1;
    GEMM_STAGE(nb, imin(ks + 1, 15) * 64);
    asm volatile("s_waitcnt vmcnt(6)" ::: "memory");

    const char* as = (const char*)&As[ks & 1][0];
    const char* bs = (const char*)&Bs[ks & 1][0];
    short8 afA[4], afB[4], bfA[2], bfB[2];
#pragma unroll
    for (int i = 0; i < 4; ++i) {
      afA[i] = *(const short8*)(as + i * 2048 + aoff);
      afB[i] = *(const short8*)(as + i * 2048 + coff);
    }
#pragma unroll
    for (int j = 0; j < 2; ++j) {
      bfA[j] = *(const short8*)(bs + (w * 32 + j * 16) * 128 + aoff);
      bfB[j] = *(const short8*)(bs + (w * 32 + j * 16) * 128 + coff);
    }
#pragma unroll
    for (int i = 0; i < 4; ++i)
#pragma unroll
      for (int j = 0; j < 2; ++j) {
        acc[i][j] = MFMA16(afA[i], bfA[j], acc[i][j]);
        acc[i][j] = MFMA16(afB[i], bfB[j], acc[i][j]);
      }
    __builtin_amdgcn_s_barrier();
  }
  asm volatile("s_waitcnt vmcnt(0)" ::: "memory");

#pragma unroll
  for (int j = 0; j < 2; ++j) {
    int col = n0 + w * 32 + j * 16 + l15;
    float bia = bias[col];
#pragma unroll
    for (int i = 0; i < 4; ++i) {
      int row0 = m0 + i * 16 + lhi * 4;
      if (out_bf16) {
#pragma unroll
        for (int r = 0; r < 4; ++r)
          ((short*)C)[(size_t)(row0 + r) * ldc + col] =
              (short)(pk_bf16(acc[i][j][r] + bia, 0.f) & 0xffff);
        // fused V transpose (gemm1 only, V columns): vt[b][d][pos] where
        // pos = T*64 + pi^-1(rho&63); 4-row group (y1y0=0) -> 2 packed
        // dword stores at {pb, pb+1} and {pb+32, pb+33}.
        if (vt_out != nullptr && col >= 1088) {
          const int d = col - 1088;
          const int bb = row0 >> 11, rho = row0 & 2047;
          const int T = rho >> 6, y = rho & 63;
          const int pb = 16 * ((y >> 3) & 1) + 8 * ((y >> 2) & 1) +
                         4 * ((y >> 5) & 1) + 2 * ((y >> 4) & 1);
          short* vp = vt_out + (size_t)(bb * 64 + d) * 2048 + T * 64 + pb;
          *(uint32_t*)(vp) = pk_bf16(acc[i][j][0] + bia, acc[i][j][1] + bia);
          *(uint32_t*)(vp + 32) = pk_bf16(acc[i][j][2] + bia, acc[i][j][3] + bia);
        }
      } else {
#pragma unroll
        for (int r = 0; r < 4; ++r)
          ((float*)C)[(size_t)(row0 + r) * ldc + col] = acc[i][j][r] + bia;
      }
    }
  }
#undef GEMM_STAGE
}

// ---------------- flash attention v13 (known-good) ----------------
// 8 waves (512 thr): wave w -> q-wave qw=w&3 (32 q rows = two 16-row groups
// sharing K/V frag reads) x kv-group g2=w>>2 (even/odd tiles). Block covers
// a 128-q chunk-pair; ntiles = 2p+2 (even -> clean group split). K/V LDS
// [group][dbuf] (64KB). Static-bias softmax -> merge is exact addition.
// Balanced map: CU's 2 blocks (p=g, 15-g) sum to 34 tiles.
__global__ __launch_bounds__(512, 4) void k_attn(const short* __restrict__ qkv,
                                                 const short* __restrict__ vt,
                                                 short* __restrict__ attnb) {
  // LDS: K[g2][db] at g2*16384 + db*8192 (0..32K); V same at 32768+...
  __shared__ char smem[65536];
  const int t = threadIdx.x;
  const int w = t >> 6, l = t & 63;
  const int l15 = l & 15, lhi = l >> 4;
  const int qw = w & 3, g2 = w >> 2;
  const int bx = blockIdx.x;
  const int o = bx >> 5, gg = o & 7;
  const int p = (o < 8) ? gg : 15 - gg;  // balanced: CU's 2 blocks sum 34 tiles
  const int bh = bx & 31, b = bh >> 4, h = bh & 15;
  const int nph = p + 1;
  const short* kb = qkv + (size_t)(b * 2048) * 1152 + 1024;
  const short* vb = vt + (size_t)b * 64 * 2048;

  // staging lane geometry: wave w covers rows w*8..w*8+7 (8 waves = 64 rows);
  // LDS slot (row, c) holds global chunk c ^ (row&7)
  const int srow = w * 8 + (l >> 3);
  const int gcol = (l & 7) ^ (l >> 3);
  const short* kS = kb + (size_t)srow * 1152 + gcol * 8;
  const short* vS = vb + (size_t)srow * 2048 + gcol * 8;

  // frag read byte offsets (row = f*16 + l15, row stride 128B)
  const int aoff = l15 * 128 + ((lhi ^ (l15 & 7)) << 4);
  const int coff = l15 * 128 + (((4 + lhi) ^ (l15 & 7)) << 4);

  short8 ones;
#pragma unroll
  for (int j = 0; j < 8; ++j) ones[j] = (short)0x3F80;  // bf16 1.0

  const int qbase = p * 128 + qw * 32;
  const int myq0 = qbase + l15;        // q-group A
  const int myq1 = qbase + 16 + l15;   // q-group B
  const int ttdiag = qbase >> 6;       // same for both groups (qbase%64 in {0,32})

  const short* qp0 = qkv + (size_t)(b * 2048 + myq0) * 1152 + h * 64 + 8 * lhi;
  const short* qp1 = qkv + (size_t)(b * 2048 + myq1) * 1152 + h * 64 + 8 * lhi;
  short8 qa0 = *(const short8*)(qp0);
  short8 qc0 = *(const short8*)(qp0 + 32);
  short8 qa1 = *(const short8*)(qp1);
  short8 qc1 = *(const short8*)(qp1 + 32);

  f32x4 oo[2][4], o5a, o5b;
#pragma unroll
  for (int qg = 0; qg < 2; ++qg)
#pragma unroll
    for (int fd = 0; fd < 4; ++fd)
#pragma unroll
      for (int r = 0; r < 4; ++r) oo[qg][fd][r] = 0.f;
#pragma unroll
  for (int r = 0; r < 4; ++r) { o5a[r] = 0.f; o5b[r] = 0.f; }

  // prologue: stage tiles 0 (->K[0][0],V[0][0]) and 1 (->K[1][0],V[1][0])
  gload_lds16(kS, smem + w * 1024);
  gload_lds16(kS + 73728, smem + 16384 + w * 1024);
  gload_lds16(vS, smem + 32768 + w * 1024);
  gload_lds16(vS + 64, smem + 32768 + 16384 + w * 1024);
  __syncthreads();

#pragma unroll 1
  for (int i = 0; i < nph; ++i) {
    // stage phase i+1 tiles (2i+2 -> group0 buf, 2i+3 -> group1 buf)
    if (i + 1 < nph) {
      const int nb = (i + 1) & 1;
      const size_t ko2 = (size_t)(2 * i + 2) * 73728;
      const int vo2 = (2 * i + 2) * 64;
      gload_lds16(kS + ko2, smem + nb * 8192 + w * 1024);
      gload_lds16(kS + ko2 + 73728, smem + 16384 + nb * 8192 + w * 1024);
      gload_lds16(vS + vo2, smem + 32768 + nb * 8192 + w * 1024);
      gload_lds16(vS + vo2 + 64, smem + 32768 + 16384 + nb * 8192 + w * 1024);
      __builtin_amdgcn_sched_barrier(0);
    }

    const int tt = 2 * i + g2;
    const int cb = i & 1;

    // K frags (shared by both q-groups); S^T = K Q^T for both groups
    const char* kr = smem + g2 * 16384 + cb * 8192;
    f32x4 s0[4], s1[4];
    __builtin_amdgcn_s_setprio(1);
#pragma unroll
    for (int f = 0; f < 4; ++f) {
      short8 ka = *(const short8*)(kr + f * 2048 + aoff);
      short8 kc = *(const short8*)(kr + f * 2048 + coff);
      f32x4 z0 = {0.f, 0.f, 0.f, 0.f};
      z0 = MFMA16(ka, qa0, z0);
      z0 = MFMA16(kc, qc0, z0);
      s0[f] = z0;
      f32x4 z1 = {0.f, 0.f, 0.f, 0.f};
      z1 = MFMA16(ka, qa1, z1);
      z1 = MFMA16(kc, qc1, z1);
      s1[f] = z1;
    }
    __builtin_amdgcn_s_setprio(0);

    // causal mask: needed whenever tile reaches/passes the q rows
    if (tt >= ttdiag) {
      const int t0 = tt * 64;
#pragma unroll
      for (int f = 0; f < 4; ++f) {
        int kvb = t0 + f * 16 + lhi * 4;
#pragma unroll
        for (int r = 0; r < 4; ++r) {
          s0[f][r] = (kvb + r <= myq0) ? s0[f][r] : -1e30f;
          s1[f][r] = (kvb + r <= myq1) ? s1[f][r] : -1e30f;
        }
      }
    }

    // p = exp2(s), fixed zero bias (see R12 rationale)
#pragma unroll
    for (int f = 0; f < 4; ++f)
#pragma unroll
      for (int r = 0; r < 4; ++r) {
        s0[f][r] = fast_exp2(s0[f][r]);
        s1[f][r] = fast_exp2(s1[f][r]);
      }

    union { short8 v; uint32_t d[4]; } pA0, pB0, pA1, pB1;
#pragma unroll
    for (int f = 0; f < 4; ++f) {
      pA0.d[f] = pk_bf16(s0[f][0], s0[f][1]);
      pB0.d[f] = pk_bf16(s0[f][2], s0[f][3]);
      pA1.d[f] = pk_bf16(s1[f][0], s1[f][1]);
      pB1.d[f] = pk_bf16(s1[f][2], s1[f][3]);
    }

    // V frags (shared); O^T += V^T P^T per group; l via ones-MFMA
    const char* vr = smem + 32768 + g2 * 16384 + cb * 8192;
    __builtin_amdgcn_s_setprio(1);
#pragma unroll
    for (int fd = 0; fd < 4; ++fd) {
      short8 va = *(const short8*)(vr + fd * 2048 + aoff);
      short8 vc = *(const short8*)(vr + fd * 2048 + coff);
      oo[0][fd] = MFMA16(va, pA0.v, oo[0][fd]);
      oo[0][fd] = MFMA16(vc, pB0.v, oo[0][fd]);
      oo[1][fd] = MFMA16(va, pA1.v, oo[1][fd]);
      oo[1][fd] = MFMA16(vc, pB1.v, oo[1][fd]);
    }
    o5a = MFMA16(ones, pA0.v, o5a);
    o5a = MFMA16(ones, pB0.v, o5a);
    o5b = MFMA16(ones, pA1.v, o5b);
    o5b = MFMA16(ones, pB1.v, o5b);
    __builtin_amdgcn_s_setprio(0);

    __syncthreads();  // staged tiles landed; all reads of current bufs done
  }

  // merge groups (exact addition thanks to fixed-bias softmax), write out.
  // scratch overlaps K bufs (safe: after final barrier, compute done).
  float* scr = (float*)smem;
  float* sp = scr + ((qw << 6) + l) * 34;
  if (g2 == 1) {
#pragma unroll
    for (int qg = 0; qg < 2; ++qg)
#pragma unroll
      for (int fd = 0; fd < 4; ++fd)
#pragma unroll
        for (int r = 0; r < 4; ++r) sp[qg * 16 + fd * 4 + r] = oo[qg][fd][r];
    sp[32] = o5a[0];
    sp[33] = o5b[0];
  }
  __syncthreads();
  if (g2 == 0) {
#pragma unroll
    for (int qg = 0; qg < 2; ++qg) {
      float lsum = (qg ? o5b[0] : o5a[0]) + sp[32 + qg];
      float inv = 1.f / lsum;
      int myq = qbase + qg * 16 + l15;
      short* op = attnb + (size_t)(b * 2048 + myq) * 1024 + h * 64;
#pragma unroll
      for (int fd = 0; fd < 4; ++fd) {
        union { short4_t s4; uint32_t d[2]; } ov;
        float v0 = (oo[qg][fd][0] + sp[qg * 16 + fd * 4 + 0]) * inv;
        float v1 = (oo[qg][fd][1] + sp[qg * 16 + fd * 4 + 1]) * inv;
        float v2 = (oo[qg][fd][2] + sp[qg * 16 + fd * 4 + 2]) * inv;
        float v3 = (oo[qg][fd][3] + sp[qg * 16 + fd * 4 + 3]) * inv;
        ov.d[0] = pk_bf16(v0, v1);
        ov.d[1] = pk_bf16(v2, v3);
        *(short4_t*)(op + fd * 16 + lhi * 4) = ov.s4;
      }
    }
  }
}

// ---------------- launch ----------------
extern "C" void kernel_launch(void* const* d_in, const int* in_sizes, int n_in,
                              void* d_out, int out_size, void* d_ws, size_t ws_size,
                              hipStream_t stream) {
  const float* x  = (const float*)d_in[0];
  // d_in[1] = mask (causal tril) -- applied analytically
  const float* wq = (const float*)d_in[2];
  const float* bq = (const float*)d_in[3];
  const float* wk = (const float*)d_in[4];
  const float* bk = (const float*)d_in[5];
  const float* wv = (const float*)d_in[6];
  const float* bv = (const float*)d_in[7];
  const float* wo = (const float*)d_in[8];
  const float* bo = (const float*)d_in[9];

  char* ws = (char*)d_ws;
  short* xb    = (short*)(ws + 0);          // [4096][1024] bf16   8 MB
  short* qkv   = (short*)(ws + 8388608);    // [4096][1152] bf16   9 MB
  short* wqkvt = (short*)(ws + 17825792);   // [1152][1024] bf16   2.25 MB
  short* wot   = (short*)(ws + 20185088);   // [1024][1024] bf16   2 MB
  short* vt    = (short*)(ws + 22282240);   // [2][64][2048] bf16  0.5 MB
  short* attnb = (short*)(ws + 22806528);   // [4096][1024] bf16   8 MB
  float* biasq = (float*)(ws + 31195136);   // [1152] f32

  k_prep<<<1057, 256, 0, stream>>>(x, wq, wk, wv, bq, bk, bv, wo,
                                   xb, wqkvt, biasq, wot);
  k_gemm<<<dim3(64, 9), 256, 0, stream>>>(xb, wqkvt, biasq, qkv, 1152, 1, vt);
  k_attn<<<512, 512, 0, stream>>>(qkv, vt, attnb);
  k_gemm<<<dim3(64, 8), 256, 0, stream>>>(attnb, wot, bo, d_out, 1024, 0,
                                          nullptr);
}